// Round 8
// baseline (431.183 us; speedup 1.0000x reference)
//
#include <hip/hip_runtime.h>
#include <hip/hip_fp16.h>
#include <math.h>

// ---------------------------------------------------------------------------
// TacticalGAT round 29: remove two whole passes from the un-profiled middle.
// r28 locked both GAT kernels at their measured optima (gat1 46us top kernel;
// all else <46).  Now: (1) cvt_f32_f16_k deleted - mfma_linear2<128> loads
// f32 X fragments directly and converts in-register (bit-identical A frags,
// X re-reads L2-absorbed); (2) loopattr_k's full 13.6MB erec re-scan deleted
// - fill_k atomically accumulates per-node f32 attr sums (600KB L2-resident,
// same pattern as hist_k's atomics) and a 1-thread/node kernel writes the
// self-loop records (mean now over f32 attrs = closer to reference).
// GAT kernels + everything else unchanged from r28.
// ---------------------------------------------------------------------------

union H2U { __half2 h; unsigned u; };
typedef _Float16 hv2_t __attribute__((ext_vector_type(2)));
typedef unsigned uv4_t __attribute__((ext_vector_type(4)));
typedef _Float16 f16x8 __attribute__((ext_vector_type(8)));
typedef float f32x4 __attribute__((ext_vector_type(4)));

__device__ __forceinline__ __half2 hmax2(__half2 a, __half2 b) {
  union { __half2 h; hv2_t v; } x, y, r;
  x.h = a; y.h = b;
  r.v = __builtin_elementwise_max(x.v, y.v);
  return r.h;
}

#if __has_builtin(__builtin_amdgcn_fdot2)
__device__ __forceinline__ float dot2f(__half2 a, __half2 b, float c) {
  union { __half2 h; hv2_t v; } x, y;
  x.h = a; y.h = b;
  return __builtin_amdgcn_fdot2(x.v, y.v, c, false);
}
#else
__device__ __forceinline__ float dot2f(__half2 a, __half2 b, float c) {
  float2 af = __half22float2(a), bf = __half22float2(b);
  return fmaf(af.x, bf.x, fmaf(af.y, bf.y, c));
}
#endif

// raw v_exp_f32 (2^x, one instruction)
#if __has_builtin(__builtin_amdgcn_exp2f)
__device__ __forceinline__ float fexp2(float x) { return __builtin_amdgcn_exp2f(x); }
#else
__device__ __forceinline__ float fexp2(float x) { return exp2f(x); }
#endif

#if __has_builtin(__builtin_amdgcn_update_dpp)
template <int CTRL>
__device__ __forceinline__ float dpp_add(float v) {
  int r = __builtin_amdgcn_update_dpp(0, __builtin_bit_cast(int, v),
                                      CTRL, 0xf, 0xf, true);
  return v + __builtin_bit_cast(float, r);
}
// sum over 16-lane DPP row (pure VALU).
__device__ __forceinline__ float row_sum16(float v) {
  v = dpp_add<0x121>(v);  // row_ror:1
  v = dpp_add<0x122>(v);  // row_ror:2
  v = dpp_add<0x124>(v);  // row_ror:4
  v = dpp_add<0x128>(v);  // row_ror:8
  return v;
}
#else
__device__ __forceinline__ float row_sum16(float v) {
  v += __shfl_xor(v, 1);
  v += __shfl_xor(v, 2);
  v += __shfl_xor(v, 4);
  v += __shfl_xor(v, 8);
  return v;
}
#endif

__device__ __forceinline__ float eluf(float x) {
  return x > 0.f ? x : __expf(x) - 1.0f;
}

// 8 contiguous f32 -> f16x8 fragment (same rounding as the old cvt pass)
__device__ __forceinline__ f16x8 cvt8(const float* __restrict__ p) {
  float4 v0 = *(const float4*)p;
  float4 v1 = *(const float4*)(p + 4);
  H2U h0, h1, h2, h3;
  h0.h = __floats2half2_rn(v0.x, v0.y);
  h1.h = __floats2half2_rn(v0.z, v0.w);
  h2.h = __floats2half2_rn(v1.x, v1.y);
  h3.h = __floats2half2_rn(v1.z, v1.w);
  union { uv4_t u; f16x8 v; } r;
  r.u = (uv4_t){h0.u, h1.u, h2.u, h3.u};
  return r.v;
}

#define LOG2E 1.44269504088896f

// ---------------- CSR build -------------------------------------------------
__global__ void hist_k(const int* __restrict__ dst, int* __restrict__ deg,
                       int* __restrict__ rank, int E) {
  int e = blockIdx.x * 256 + threadIdx.x;
  if (e < E) rank[e] = atomicAdd(&deg[dst[e]], 1);
}

__global__ void blocksum_k(const int* __restrict__ deg, int* __restrict__ bsum, int N) {
  __shared__ int s[256];
  int i = blockIdx.x * 256 + threadIdx.x;
  s[threadIdx.x] = (i < N) ? deg[i] : 0;
  __syncthreads();
  for (int off = 128; off; off >>= 1) {
    if (threadIdx.x < off) s[threadIdx.x] += s[threadIdx.x + off];
    __syncthreads();
  }
  if (threadIdx.x == 0) bsum[blockIdx.x] = s[0];
}

// rowptr over deg+1 slots per node (self-loop slot at rowptr[n+1]-1).
__global__ void writeptr_k(const int* __restrict__ deg, const int* __restrict__ bsum,
                           int* __restrict__ rowptr, int N, int E) {
  __shared__ int s[256];
  __shared__ int bs[256];
  int t = threadIdx.x;
  int i = blockIdx.x * 256 + t;
  bs[t] = (t < (int)blockIdx.x) ? bsum[t] : 0;
  s[t] = (i < N) ? deg[i] : 0;
  __syncthreads();
  for (int off = 128; off; off >>= 1) {
    if (t < off) bs[t] += bs[t + off];
    __syncthreads();
  }
  int base = bs[0];
  __syncthreads();
  for (int off = 1; off < 256; off <<= 1) {
    int v = (t >= off) ? s[t - off] : 0;
    __syncthreads();
    if (t >= off) s[t] += v;
    __syncthreads();
  }
  int excl = base + ((t == 0) ? 0 : s[t - 1]) + i;
  if (i < N) rowptr[i] = excl;
  if (i == N - 1) rowptr[N] = E + N;
}

// edge record: {src, splat(ea0), splat(ea1), splat(ea2)} = 16B; also
// accumulates per-node f32 attr sums for the self-loop mean (no erec rescan).
__global__ void fill_k(const int* __restrict__ src, const int* __restrict__ dst,
                       const float* __restrict__ eattr, const int* __restrict__ rowptr,
                       const int* __restrict__ rank, uint4* __restrict__ erec,
                       float* __restrict__ asum, int E) {
  int e = blockIdx.x * 256 + threadIdx.x;
  if (e >= E) return;
  int d = dst[e];
  int pos = rowptr[d] + rank[e];
  H2U a0, a1, a2;
  float e0 = eattr[e * 3 + 0], e1 = eattr[e * 3 + 1], e2 = eattr[e * 3 + 2];
  a0.h = __floats2half2_rn(e0, e0);
  a1.h = __floats2half2_rn(e1, e1);
  a2.h = __floats2half2_rn(e2, e2);
  uv4_t v = {(unsigned)src[e], a0.u, a1.u, a2.u};
  __builtin_nontemporal_store(v, (uv4_t*)&erec[pos]);
  atomicAdd(&asum[d * 3 + 0], e0);
  atomicAdd(&asum[d * 3 + 1], e1);
  atomicAdd(&asum[d * 3 + 2], e2);
}

// one thread per node: write self-loop record from the accumulated mean.
__global__ void loopattr2_k(const int* __restrict__ rowptr,
                            const float* __restrict__ asum,
                            uint4* __restrict__ erec, int N) {
  int n = blockIdx.x * 256 + threadIdx.x;
  if (n >= N) return;
  int beg = rowptr[n], endr = rowptr[n + 1] - 1;  // self-loop slot
  float inv = 1.0f / fmaxf((float)(endr - beg), 1.0f);
  float f0 = asum[n * 3 + 0] * inv;
  float f1 = asum[n * 3 + 1] * inv;
  float f2 = asum[n * 3 + 2] * inv;
  H2U a0, a1, a2;
  a0.h = __floats2half2_rn(f0, f0);
  a1.h = __floats2half2_rn(f1, f1);
  a2.h = __floats2half2_rn(f2, f2);
  erec[endr] = make_uint4((unsigned)n, a0.u, a1.u, a2.u);
}

// all four GAT weight matrices -> two f16 tables (one launch, 6144 threads)
__global__ void cvt_w_all_k(const float* __restrict__ Wl1, const float* __restrict__ Wr1,
                            const float* __restrict__ Wl2, const float* __restrict__ Wr2,
                            __half* __restrict__ wh1, __half* __restrict__ wh2) {
  int i = blockIdx.x * 256 + threadIdx.x;
  if (i >= 6144) return;
  const float* s;
  __half* d;
  int off;
  if (i < 2048)      { s = Wl1; d = wh1;         off = i; }
  else if (i < 4096) { s = Wr1; d = wh1 + 16384; off = i - 2048; }
  else if (i < 5120) { s = Wl2; d = wh2;         off = i - 4096; }
  else               { s = Wr2; d = wh2 + 8192;  off = i - 5120; }
  const float4* sp = (const float4*)(s + (size_t)off * 8);
  float4 v0 = sp[0], v1 = sp[1];
  H2U h0, h1, h2, h3;
  h0.h = __floats2half2_rn(v0.x, v0.y);
  h1.h = __floats2half2_rn(v0.z, v0.w);
  h2.h = __floats2half2_rn(v1.x, v1.y);
  h3.h = __floats2half2_rn(v1.z, v1.w);
  uv4_t o = {h0.u, h1.u, h2.u, h3.u};
  *(uv4_t*)(d + (size_t)off * 8) = o;
}

// ---------------- MFMA dual node linear (K=128, f16 out) --------------------
// Wave tile: 32 rows x 64 cols; Wh = [2J][128] f16 (rows 0..J-1 = table 1).
// F32IN: A-fragments loaded from f32 X and converted in-register (identical
// rounding to the old pre-convert pass).  No LDS, no barriers.
template <int J, bool F32IN>
__global__ __launch_bounds__(256) void mfma_linear2_k(
    const void* __restrict__ Xin, const __half* __restrict__ Wh,
    const float* __restrict__ b1v, const float* __restrict__ b2v,
    __half* __restrict__ out1, __half* __restrict__ out2, int N) {
  constexpr int CG = (2 * J) / 64;  // 64-col groups across both tables
  int lane = threadIdx.x & 63;
  int wid = __builtin_amdgcn_readfirstlane(
      (int)((blockIdx.x * 256 + threadIdx.x) >> 6));
  int rt = wid / CG;
  int cg = wid - rt * CG;
  int r0 = rt * 32;
  if (r0 >= N) return;

  int koff = (lane >> 4) * 8;           // 8 contiguous k per lane-group
  int row0 = r0 + (lane & 15);
  int row1 = row0 + 16;
  int cr0 = min(row0, N - 1), cr1 = min(row1, N - 1);

  f16x8 a0[4], a1[4];
  if (F32IN) {
    const float* Xf = (const float*)Xin;
    const float* xp0 = Xf + (size_t)cr0 * 128 + koff;
    const float* xp1 = Xf + (size_t)cr1 * 128 + koff;
#pragma unroll
    for (int ks = 0; ks < 4; ++ks) {
      a0[ks] = cvt8(xp0 + ks * 32);
      a1[ks] = cvt8(xp1 + ks * 32);
    }
  } else {
    const __half* Xh = (const __half*)Xin;
    const __half* xp0 = Xh + (size_t)cr0 * 128 + koff;
    const __half* xp1 = Xh + (size_t)cr1 * 128 + koff;
#pragma unroll
    for (int ks = 0; ks < 4; ++ks) {
      a0[ks] = *(const f16x8*)(xp0 + ks * 32);
      a1[ks] = *(const f16x8*)(xp1 + ks * 32);
    }
  }

  bool isT1 = (cg * 64) < J;            // whole 64-col group in one table
  const float* bt = isT1 ? b1v : b2v;
  __half* op = isT1 ? out1 : out2;
  int cbase = cg * 64 - (isT1 ? 0 : J);
  int cl = cbase + (lane & 15);
  int rA = r0 + ((lane >> 4) << 2);

#pragma unroll
  for (int ct = 0; ct < 4; ++ct) {
    int col = cg * 64 + ct * 16 + (lane & 15);
    const __half* wp = Wh + (size_t)col * 128 + koff;
    f16x8 b0 = *(const f16x8*)(wp);
    f16x8 b1_ = *(const f16x8*)(wp + 32);
    f16x8 b2_ = *(const f16x8*)(wp + 64);
    f16x8 b3_ = *(const f16x8*)(wp + 96);
    f32x4 acc0 = {0.f, 0.f, 0.f, 0.f};
    f32x4 acc1 = {0.f, 0.f, 0.f, 0.f};
    acc0 = __builtin_amdgcn_mfma_f32_16x16x32_f16(a0[0], b0, acc0, 0, 0, 0);
    acc1 = __builtin_amdgcn_mfma_f32_16x16x32_f16(a1[0], b0, acc1, 0, 0, 0);
    acc0 = __builtin_amdgcn_mfma_f32_16x16x32_f16(a0[1], b1_, acc0, 0, 0, 0);
    acc1 = __builtin_amdgcn_mfma_f32_16x16x32_f16(a1[1], b1_, acc1, 0, 0, 0);
    acc0 = __builtin_amdgcn_mfma_f32_16x16x32_f16(a0[2], b2_, acc0, 0, 0, 0);
    acc1 = __builtin_amdgcn_mfma_f32_16x16x32_f16(a1[2], b2_, acc1, 0, 0, 0);
    acc0 = __builtin_amdgcn_mfma_f32_16x16x32_f16(a0[3], b3_, acc0, 0, 0, 0);
    acc1 = __builtin_amdgcn_mfma_f32_16x16x32_f16(a1[3], b3_, acc1, 0, 0, 0);

    int cc = cl + ct * 16;
    float bb = bt[cc];
#pragma unroll
    for (int q = 0; q < 4; ++q) {
      int r = rA + q;
      if (r < N) op[(size_t)r * J + cc] = __float2half(acc0[q] + bb);
      int r2 = r + 16;
      if (r2 < N) op[(size_t)r2 * J + cc] = __float2half(acc1[q] + bb);
    }
  }
}

// ---------------- fused GATv2 layer 1 (H=4, C=32, concat) -------------------
// r24 structure: one wave per node, scalar (SGPR) rec loads, broadcast
// gathers (2 ch/lane), CH=8 flat chunks; tail = batched quad (if rem>=4)
// + pairs + single, in edge order.  f16 output.
__global__ __launch_bounds__(128) void gat1_fused_k(
    const int* __restrict__ rowptr, const uint4* __restrict__ erec,
    const __half* __restrict__ xlh, const __half* __restrict__ xrh,
    const float* __restrict__ We, const float* __restrict__ att,
    const float* __restrict__ bias, __half* __restrict__ out, int N) {
  constexpr int CH = 8;
  int lane = threadIdx.x & 63;
  int wave0 = __builtin_amdgcn_readfirstlane(
      (int)((blockIdx.x * blockDim.x + threadIdx.x) >> 6));
  int nwaves = (gridDim.x * blockDim.x) >> 6;
  const __half2* xl2p = (const __half2*)xlh;
  const __half2* xr2p = (const __half2*)xrh;
  __half2* outp = (__half2*)out;
  int c0 = 2 * lane;
  __half2 w0p = __floats2half2_rn(We[c0 * 3 + 0], We[c0 * 3 + 3]);
  __half2 w1p = __floats2half2_rn(We[c0 * 3 + 1], We[c0 * 3 + 4]);
  __half2 w2p = __floats2half2_rn(We[c0 * 3 + 2], We[c0 * 3 + 5]);
  __half2 attp = __floats2half2_rn(att[c0] * LOG2E, att[c0 + 1] * LOG2E);
  __half2 k02 = __floats2half2_rn(0.2f, 0.2f);
  float2 bv = make_float2(bias[c0], bias[c0 + 1]);

  for (int n = wave0; n < N; n += nwaves) {
    __half2 xrp = xr2p[(size_t)n * 64 + lane];
    int beg = rowptr[n], end = rowptr[n + 1];
    int cnt = end - beg;  // deg + 1 (self-loop included)

    float acc0 = 0.f, acc1 = 0.f, den = 0.f;

    auto edge1 = [&](const uint4& rec, __half2 rf) {
      H2U e0, e1, e2;
      e0.u = rec.y; e1.u = rec.z; e2.u = rec.w;
      __half2 m = __hadd2(rf, xrp);
      m = __hfma2(e0.h, w0p, m);
      m = __hfma2(e1.h, w1p, m);
      m = __hfma2(e2.h, w2p, m);
      m = hmax2(m, __hmul2(m, k02));
      float v = row_sum16(dot2f(m, attp, 0.f));
      float ex = fexp2(v);
      float2 rfF = __half22float2(rf);
      den += ex;
      acc0 = fmaf(ex, rfF.x, acc0);
      acc1 = fmaf(ex, rfF.y, acc1);
    };

    int nfull = cnt / CH;
    for (int ch = 0; ch < nfull; ++ch) {
      int b = beg + ch * CH;
      uint4 recs[CH];
#pragma unroll
      for (int j = 0; j < CH; ++j) recs[j] = erec[b + j];
      __half2 r_[CH];
#pragma unroll
      for (int j = 0; j < CH; ++j) {
        int s = __builtin_amdgcn_readfirstlane((int)recs[j].x);
        r_[j] = xl2p[(size_t)s * 64 + lane];
      }
#pragma unroll
      for (int j = 0; j < CH; ++j) edge1(recs[j], r_[j]);
    }
    int gi = beg + nfull * CH;
    // batched quad stage (rem >= 4)
    if (gi + 4 <= end) {
      uint4 recs[4];
#pragma unroll
      for (int j = 0; j < 4; ++j) recs[j] = erec[gi + j];
      __half2 r_[4];
#pragma unroll
      for (int j = 0; j < 4; ++j) {
        int s = __builtin_amdgcn_readfirstlane((int)recs[j].x);
        r_[j] = xl2p[(size_t)s * 64 + lane];
      }
#pragma unroll
      for (int j = 0; j < 4; ++j) edge1(recs[j], r_[j]);
      gi += 4;
    }
    // pairs + optional single
    for (; gi + 2 <= end; gi += 2) {
      uint4 recA = erec[gi];
      uint4 recB = erec[gi + 1];
      int sA = __builtin_amdgcn_readfirstlane((int)recA.x);
      int sB = __builtin_amdgcn_readfirstlane((int)recB.x);
      __half2 rfA = xl2p[(size_t)sA * 64 + lane];
      __half2 rfB = xl2p[(size_t)sB * 64 + lane];
      edge1(recA, rfA);
      edge1(recB, rfB);
    }
    if (gi < end) {
      uint4 rec = erec[gi];
      int s = __builtin_amdgcn_readfirstlane((int)rec.x);
      __half2 rf = xl2p[(size_t)s * 64 + lane];
      edge1(rec, rf);
    }

    float o0 = acc0 / den + bv.x;
    float o1 = acc1 / den + bv.y;
    o0 = o0 > 0.f ? o0 : __expf(o0) - 1.0f;  // ELU
    o1 = o1 > 0.f ? o1 : __expf(o1) - 1.0f;
    H2U o;
    o.h = __floats2half2_rn(o0, o1);
    outp[(size_t)n * 64 + lane] = o.h;
  }
}

// ---------------- fused GATv2 layer 2 (H=1, C=64, mean) ---------------------
// One wave per node; 4 edges/wave (16 lanes each, 4 ch/lane); score reduce =
// row_sum16 only; exp/den amortize 4x.  f32 output.  (r27 version - won.)
__global__ __launch_bounds__(128) void gat2_fused_k(
    const int* __restrict__ rowptr, const uint4* __restrict__ erec,
    const __half* __restrict__ xlh, const __half* __restrict__ xrh,
    const float* __restrict__ We, const float* __restrict__ att,
    const float* __restrict__ bias, float* __restrict__ out, int N) {
  int lane = threadIdx.x & 63;
  int s16 = lane & 15, qr = lane >> 4;  // quarter 0..3
  int wave0 = __builtin_amdgcn_readfirstlane(
      (int)((blockIdx.x * blockDim.x + threadIdx.x) >> 6));
  int nwaves = (gridDim.x * blockDim.x) >> 6;
  int c4 = s16 * 4;  // this lane's 4 channels of 64

  __half2 w0A = __floats2half2_rn(We[(c4 + 0) * 3 + 0], We[(c4 + 1) * 3 + 0]);
  __half2 w0B = __floats2half2_rn(We[(c4 + 2) * 3 + 0], We[(c4 + 3) * 3 + 0]);
  __half2 w1A = __floats2half2_rn(We[(c4 + 0) * 3 + 1], We[(c4 + 1) * 3 + 1]);
  __half2 w1B = __floats2half2_rn(We[(c4 + 2) * 3 + 1], We[(c4 + 3) * 3 + 1]);
  __half2 w2A = __floats2half2_rn(We[(c4 + 0) * 3 + 2], We[(c4 + 1) * 3 + 2]);
  __half2 w2B = __floats2half2_rn(We[(c4 + 2) * 3 + 2], We[(c4 + 3) * 3 + 2]);
  __half2 attA = __floats2half2_rn(att[c4 + 0] * LOG2E, att[c4 + 1] * LOG2E);
  __half2 attB = __floats2half2_rn(att[c4 + 2] * LOG2E, att[c4 + 3] * LOG2E);
  __half2 k02 = __floats2half2_rn(0.2f, 0.2f);
  float4 bvv = make_float4(bias[c4], bias[c4 + 1], bias[c4 + 2], bias[c4 + 3]);

  for (int n = wave0; n < N; n += nwaves) {
    uint2 xu = *(const uint2*)&xrh[(size_t)n * 64 + c4];
    H2U xrA, xrB;
    xrA.u = xu.x; xrB.u = xu.y;
    int beg = rowptr[n], end = rowptr[n + 1];
    int cnt = end - beg;  // deg + 1
    float a0 = 0.f, a1 = 0.f, a2 = 0.f, a3 = 0.f, den = 0.f;

    auto edge4 = [&](const uint4& rec, uint2 gu, bool valid) {
      H2U e0, e1, e2, gA, gB;
      e0.u = rec.y; e1.u = rec.z; e2.u = rec.w;
      gA.u = gu.x; gB.u = gu.y;
      __half2 tA = __hfma2(e2.h, w2A, xrA.h);
      tA = __hfma2(e1.h, w1A, tA);
      tA = __hfma2(e0.h, w0A, tA);
      __half2 mA = __hadd2(gA.h, tA);
      mA = hmax2(mA, __hmul2(mA, k02));
      __half2 tB = __hfma2(e2.h, w2B, xrB.h);
      tB = __hfma2(e1.h, w1B, tB);
      tB = __hfma2(e0.h, w0B, tB);
      __half2 mB = __hadd2(gB.h, tB);
      mB = hmax2(mB, __hmul2(mB, k02));
      float v = dot2f(mB, attB, dot2f(mA, attA, 0.f));
      v = row_sum16(v);
      float ex = valid ? fexp2(v) : 0.f;
      float2 fA = __half22float2(gA.h), fB = __half22float2(gB.h);
      den += ex;
      a0 = fmaf(ex, fA.x, a0);
      a1 = fmaf(ex, fA.y, a1);
      a2 = fmaf(ex, fB.x, a2);
      a3 = fmaf(ex, fB.y, a3);
    };

    int nch = cnt >> 3;  // chunks of 8 edges = 2 quads
    for (int ch = 0; ch < nch; ++ch) {
      int b = beg + ch * 8 + qr;
      uint4 rec[2];
      uint2 gu[2];
#pragma unroll
      for (int j = 0; j < 2; ++j) rec[j] = erec[b + 4 * j];
#pragma unroll
      for (int j = 0; j < 2; ++j)
        gu[j] = *(const uint2*)(xlh + (size_t)rec[j].x * 64 + c4);
#pragma unroll
      for (int j = 0; j < 2; ++j) edge4(rec[j], gu[j], true);
    }
    // tail quads: invalid quarters masked
    for (int gi = beg + nch * 8; gi < end; gi += 4) {
      int idx = gi + qr;
      bool valid = idx < end;
      uint4 rec = erec[valid ? idx : (end - 1)];
      uint2 gu = *(const uint2*)(xlh + (size_t)rec.x * 64 + c4);
      edge4(rec, gu, valid);
    }

    // combine the four quarters
    a0 += __shfl_xor(a0, 16); a0 += __shfl_xor(a0, 32);
    a1 += __shfl_xor(a1, 16); a1 += __shfl_xor(a1, 32);
    a2 += __shfl_xor(a2, 16); a2 += __shfl_xor(a2, 32);
    a3 += __shfl_xor(a3, 16); a3 += __shfl_xor(a3, 32);
    den += __shfl_xor(den, 16); den += __shfl_xor(den, 32);

    if (lane < 16) {
      float4 o;
      o.x = eluf(a0 / den + bvv.x);
      o.y = eluf(a1 / den + bvv.y);
      o.z = eluf(a2 / den + bvv.z);
      o.w = eluf(a3 / den + bvv.w);
      *(float4*)&out[(size_t)n * 64 + c4] = o;
    }
  }
}

// ---------------- fused mean-pool + MLP head (block per graph, 256 thr) -----
__global__ void final_mlp_k(const float* __restrict__ h2, const int* __restrict__ batch,
                            int N, const float* __restrict__ u,
                            const float* __restrict__ W1, const float* __restrict__ b1,
                            const float* __restrict__ Wh, const float* __restrict__ bh,
                            float* __restrict__ out) {
  __shared__ float comb[4][64];
  __shared__ float feat[65];
  __shared__ float z[32];
  int g = blockIdx.x;
  int t = threadIdx.x;  // 256 threads
  int c = t & 63, q = t >> 6;
  int lo, hi;
  {
    int l = 0, h = N;
    while (l < h) { int m = (l + h) >> 1; if (batch[m] < g) l = m + 1; else h = m; }
    lo = l;
    h = N;
    while (l < h) { int m = (l + h) >> 1; if (batch[m] < g + 1) l = m + 1; else h = m; }
    hi = l;
  }
  float a = 0.f;
  for (int nn = lo + q; nn < hi; nn += 4) a += h2[(size_t)nn * 64 + c];
  comb[q][c] = a;
  __syncthreads();
  if (t < 64) {
    float s = comb[0][t] + comb[1][t] + comb[2][t] + comb[3][t];
    float inv = 1.0f / fmaxf((float)(hi - lo), 1.0f);
    feat[t] = s * inv;
    if (t == 0) feat[64] = u[g];
  }
  __syncthreads();
  if (t < 32) {
    float s = b1[t];
    for (int k = 0; k < 65; ++k) s += feat[k] * W1[t * 65 + k];
    z[t] = fmaxf(s, 0.0f);
  }
  __syncthreads();
  if (t < 10) {
    float s = bh[t];
    for (int k = 0; k < 32; ++k) s += z[k] * Wh[t * 32 + k];
    out[g * 10 + t] = s;
  }
}

// ---------------------------------------------------------------------------
extern "C" void kernel_launch(void* const* d_in, const int* in_sizes, int n_in,
                              void* d_out, int out_size, void* d_ws, size_t ws_size,
                              hipStream_t stream) {
  const float* x      = (const float*)d_in[0];
  const int*   eidx   = (const int*)d_in[1];
  const float* eattr  = (const float*)d_in[2];
  const int*   batch  = (const int*)d_in[3];
  const float* u      = (const float*)d_in[4];
  const float* Wl1    = (const float*)d_in[5];
  const float* bl1    = (const float*)d_in[6];
  const float* Wr1    = (const float*)d_in[7];
  const float* br1    = (const float*)d_in[8];
  const float* We1    = (const float*)d_in[9];
  const float* att1   = (const float*)d_in[10];
  const float* b1     = (const float*)d_in[11];
  const float* Wl2    = (const float*)d_in[12];
  const float* bl2    = (const float*)d_in[13];
  const float* Wr2    = (const float*)d_in[14];
  const float* br2    = (const float*)d_in[15];
  const float* We2    = (const float*)d_in[16];
  const float* att2   = (const float*)d_in[17];
  const float* b2     = (const float*)d_in[18];
  const float* W_lin1 = (const float*)d_in[19];
  const float* b_lin1 = (const float*)d_in[20];
  const float* W_head = (const float*)d_in[21];
  const float* b_head = (const float*)d_in[22];

  const int N = in_sizes[0] / 128;
  const int E = in_sizes[1] / 2;
  const int G = in_sizes[4];
  const int* srcp = eidx;
  const int* dstp = eidx + E;

  // ---- workspace layout ----
  __half* bufh = (__half*)d_ws;                     // xl table (N*128 half max)
  __half* bufr = bufh + (size_t)N * 128;            // xr table
  float* buf3 = (float*)(bufr + (size_t)N * 128);   // region: g1h f16 / h2 f32
  __half* g1h = (__half*)buf3;                      // gat1 out f16 [N,128]
  float* h2f = (float*)(g1h + (size_t)N * 128);     // gat2 out f32 [N,64]
  uint4* erec = (uint4*)(buf3 + (size_t)N * 128);   // E+N records (16B)
  int* rank   = (int*)(erec + ((size_t)E + N));     // E
  int* deg    = rank + E;                           // N
  int* rowptr = deg + N;                            // N+1
  int* bsum   = rowptr + N + 1;                     // 256
  uintptr_t wtop = ((uintptr_t)(bsum + 256) + 15) & ~(uintptr_t)15;
  __half* wh1 = (__half*)wtop;                      // [256][128] f16 = 64 KB
  __half* wh2 = wh1 + 32768;                        // [128][128] f16 = 32 KB
  float* asum = (float*)(wh2 + 16384);              // [N][3] f32 attr sums

  const int nb = (N + 255) / 256;
  const int gat_blocks = (N + 1) / 2;               // 1 wave/node, 128-thr blks
  const int rt = (N + 31) / 32;                     // 32-row MFMA tiles

  // ---- weight tables + layer-1 MFMA linear (reads f32 X directly) ----
  cvt_w_all_k<<<24, 256, 0, stream>>>(Wl1, Wr1, Wl2, Wr2, wh1, wh2);
  mfma_linear2_k<128, true><<<rt, 256, 0, stream>>>(x, wh1, bl1, br1,
                                                    bufh, bufr, N);

  // ---- CSR build ----
  (void)hipMemsetAsync(deg, 0, sizeof(int) * (size_t)N, stream);
  (void)hipMemsetAsync(asum, 0, sizeof(float) * 3 * (size_t)N, stream);
  hist_k<<<(E + 255) / 256, 256, 0, stream>>>(dstp, deg, rank, E);
  blocksum_k<<<nb, 256, 0, stream>>>(deg, bsum, N);
  writeptr_k<<<nb, 256, 0, stream>>>(deg, bsum, rowptr, N, E);
  fill_k<<<(E + 255) / 256, 256, 0, stream>>>(srcp, dstp, eattr, rowptr, rank,
                                              erec, asum, E);
  loopattr2_k<<<nb, 256, 0, stream>>>(rowptr, asum, erec, N);

  // ---- layer 1 attention ----
  gat1_fused_k<<<gat_blocks, 128, 0, stream>>>(rowptr, erec, bufh, bufr,
                                               We1, att1, b1, g1h, N);

  // ---- layer 2 linear (MFMA) + attention ----
  mfma_linear2_k<64, false><<<(rt * 2 + 3) / 4, 256, 0, stream>>>(g1h, wh2,
                                                                  bl2, br2,
                                                                  bufh, bufr, N);
  gat2_fused_k<<<gat_blocks, 128, 0, stream>>>(rowptr, erec, bufh, bufr,
                                               We2, att2, b2, h2f, N);

  // ---- fused pool + head ----
  final_mlp_k<<<G, 256, 0, stream>>>(h2f, batch, N, u, W_lin1, b_lin1, W_head, b_head,
                                     (float*)d_out);
}

// Round 9
// 333.337 us; speedup vs baseline: 1.2935x; 1.2935x over previous
//
#include <hip/hip_runtime.h>
#include <hip/hip_fp16.h>
#include <math.h>

// ---------------------------------------------------------------------------
// TacticalGAT round 30: keep r29's win, revert its loss.
// r29 post-mortem: fill_k's 3 f32 atomicAdds/edge caused full-line HBM
// write-through (WRITE_SIZE ~E*128B = 101MB, fill_k 25->128us) - device-scope
// float atomics + scattered 16B stores defeat L2 write combining; r28's plain
// scatter stayed L2-combined.  The F32IN mfma_linear2 change was fine
// (absmax unchanged).  So: fill_k + loopattr_k reverted to r28's exact
// versions; cvt_f32_f16_k stays deleted (mfma_linear2<128,true> reads f32 X
// directly, in-register convert).  Everything else = r28.
// ---------------------------------------------------------------------------

union H2U { __half2 h; unsigned u; };
typedef _Float16 hv2_t __attribute__((ext_vector_type(2)));
typedef unsigned uv4_t __attribute__((ext_vector_type(4)));
typedef _Float16 f16x8 __attribute__((ext_vector_type(8)));
typedef float f32x4 __attribute__((ext_vector_type(4)));

__device__ __forceinline__ __half2 hmax2(__half2 a, __half2 b) {
  union { __half2 h; hv2_t v; } x, y, r;
  x.h = a; y.h = b;
  r.v = __builtin_elementwise_max(x.v, y.v);
  return r.h;
}

#if __has_builtin(__builtin_amdgcn_fdot2)
__device__ __forceinline__ float dot2f(__half2 a, __half2 b, float c) {
  union { __half2 h; hv2_t v; } x, y;
  x.h = a; y.h = b;
  return __builtin_amdgcn_fdot2(x.v, y.v, c, false);
}
#else
__device__ __forceinline__ float dot2f(__half2 a, __half2 b, float c) {
  float2 af = __half22float2(a), bf = __half22float2(b);
  return fmaf(af.x, bf.x, fmaf(af.y, bf.y, c));
}
#endif

// raw v_exp_f32 (2^x, one instruction)
#if __has_builtin(__builtin_amdgcn_exp2f)
__device__ __forceinline__ float fexp2(float x) { return __builtin_amdgcn_exp2f(x); }
#else
__device__ __forceinline__ float fexp2(float x) { return exp2f(x); }
#endif

#if __has_builtin(__builtin_amdgcn_update_dpp)
template <int CTRL>
__device__ __forceinline__ float dpp_add(float v) {
  int r = __builtin_amdgcn_update_dpp(0, __builtin_bit_cast(int, v),
                                      CTRL, 0xf, 0xf, true);
  return v + __builtin_bit_cast(float, r);
}
// sum over 16-lane DPP row (pure VALU).
__device__ __forceinline__ float row_sum16(float v) {
  v = dpp_add<0x121>(v);  // row_ror:1
  v = dpp_add<0x122>(v);  // row_ror:2
  v = dpp_add<0x124>(v);  // row_ror:4
  v = dpp_add<0x128>(v);  // row_ror:8
  return v;
}
#else
__device__ __forceinline__ float row_sum16(float v) {
  v += __shfl_xor(v, 1);
  v += __shfl_xor(v, 2);
  v += __shfl_xor(v, 4);
  v += __shfl_xor(v, 8);
  return v;
}
#endif

__device__ __forceinline__ float lowf(unsigned u) {
  H2U t; t.u = u;
  return __half2float(__low2half(t.h));
}

__device__ __forceinline__ float eluf(float x) {
  return x > 0.f ? x : __expf(x) - 1.0f;
}

// 8 contiguous f32 -> f16x8 fragment (same rounding as the old cvt pass)
__device__ __forceinline__ f16x8 cvt8(const float* __restrict__ p) {
  float4 v0 = *(const float4*)p;
  float4 v1 = *(const float4*)(p + 4);
  H2U h0, h1, h2, h3;
  h0.h = __floats2half2_rn(v0.x, v0.y);
  h1.h = __floats2half2_rn(v0.z, v0.w);
  h2.h = __floats2half2_rn(v1.x, v1.y);
  h3.h = __floats2half2_rn(v1.z, v1.w);
  union { uv4_t u; f16x8 v; } r;
  r.u = (uv4_t){h0.u, h1.u, h2.u, h3.u};
  return r.v;
}

#define LOG2E 1.44269504088896f

// ---------------- CSR build -------------------------------------------------
__global__ void hist_k(const int* __restrict__ dst, int* __restrict__ deg,
                       int* __restrict__ rank, int E) {
  int e = blockIdx.x * 256 + threadIdx.x;
  if (e < E) rank[e] = atomicAdd(&deg[dst[e]], 1);
}

__global__ void blocksum_k(const int* __restrict__ deg, int* __restrict__ bsum, int N) {
  __shared__ int s[256];
  int i = blockIdx.x * 256 + threadIdx.x;
  s[threadIdx.x] = (i < N) ? deg[i] : 0;
  __syncthreads();
  for (int off = 128; off; off >>= 1) {
    if (threadIdx.x < off) s[threadIdx.x] += s[threadIdx.x + off];
    __syncthreads();
  }
  if (threadIdx.x == 0) bsum[blockIdx.x] = s[0];
}

// rowptr over deg+1 slots per node (self-loop slot at rowptr[n+1]-1).
__global__ void writeptr_k(const int* __restrict__ deg, const int* __restrict__ bsum,
                           int* __restrict__ rowptr, int N, int E) {
  __shared__ int s[256];
  __shared__ int bs[256];
  int t = threadIdx.x;
  int i = blockIdx.x * 256 + t;
  bs[t] = (t < (int)blockIdx.x) ? bsum[t] : 0;
  s[t] = (i < N) ? deg[i] : 0;
  __syncthreads();
  for (int off = 128; off; off >>= 1) {
    if (t < off) bs[t] += bs[t + off];
    __syncthreads();
  }
  int base = bs[0];
  __syncthreads();
  for (int off = 1; off < 256; off <<= 1) {
    int v = (t >= off) ? s[t - off] : 0;
    __syncthreads();
    if (t >= off) s[t] += v;
    __syncthreads();
  }
  int excl = base + ((t == 0) ? 0 : s[t - 1]) + i;
  if (i < N) rowptr[i] = excl;
  if (i == N - 1) rowptr[N] = E + N;
}

// edge record: {src, splat(ea0), splat(ea1), splat(ea2)} = 16B; no atomics.
__global__ void fill_k(const int* __restrict__ src, const int* __restrict__ dst,
                       const float* __restrict__ eattr, const int* __restrict__ rowptr,
                       const int* __restrict__ rank, uint4* __restrict__ erec, int E) {
  int e = blockIdx.x * 256 + threadIdx.x;
  if (e >= E) return;
  int pos = rowptr[dst[e]] + rank[e];
  H2U a0, a1, a2;
  float e0 = eattr[e * 3 + 0], e1 = eattr[e * 3 + 1], e2 = eattr[e * 3 + 2];
  a0.h = __floats2half2_rn(e0, e0);
  a1.h = __floats2half2_rn(e1, e1);
  a2.h = __floats2half2_rn(e2, e2);
  uv4_t v = {(unsigned)src[e], a0.u, a1.u, a2.u};
  __builtin_nontemporal_store(v, (uv4_t*)&erec[pos]);
}

// wave per node: average the real edges' attrs, write self-loop record.
__global__ void loopattr_k(const int* __restrict__ rowptr, uint4* __restrict__ erec, int N) {
  int lane = threadIdx.x & 63;
  int n = (int)((blockIdx.x * 256 + threadIdx.x) >> 6);
  if (n >= N) return;
  int beg = rowptr[n], endr = rowptr[n + 1] - 1;  // real edges
  float f0 = 0.f, f1 = 0.f, f2 = 0.f;
  for (int i = beg + lane; i < endr; i += 64) {
    uint4 r = erec[i];
    f0 += lowf(r.y);
    f1 += lowf(r.z);
    f2 += lowf(r.w);
  }
#pragma unroll
  for (int off = 1; off < 64; off <<= 1) {
    f0 += __shfl_xor(f0, off);
    f1 += __shfl_xor(f1, off);
    f2 += __shfl_xor(f2, off);
  }
  if (lane == 0) {
    float inv = 1.0f / fmaxf((float)(endr - beg), 1.0f);
    H2U a0, a1, a2;
    a0.h = __floats2half2_rn(f0 * inv, f0 * inv);
    a1.h = __floats2half2_rn(f1 * inv, f1 * inv);
    a2.h = __floats2half2_rn(f2 * inv, f2 * inv);
    erec[endr] = make_uint4((unsigned)n, a0.u, a1.u, a2.u);
  }
}

// all four GAT weight matrices -> two f16 tables (one launch, 6144 threads)
__global__ void cvt_w_all_k(const float* __restrict__ Wl1, const float* __restrict__ Wr1,
                            const float* __restrict__ Wl2, const float* __restrict__ Wr2,
                            __half* __restrict__ wh1, __half* __restrict__ wh2) {
  int i = blockIdx.x * 256 + threadIdx.x;
  if (i >= 6144) return;
  const float* s;
  __half* d;
  int off;
  if (i < 2048)      { s = Wl1; d = wh1;         off = i; }
  else if (i < 4096) { s = Wr1; d = wh1 + 16384; off = i - 2048; }
  else if (i < 5120) { s = Wl2; d = wh2;         off = i - 4096; }
  else               { s = Wr2; d = wh2 + 8192;  off = i - 5120; }
  const float4* sp = (const float4*)(s + (size_t)off * 8);
  float4 v0 = sp[0], v1 = sp[1];
  H2U h0, h1, h2, h3;
  h0.h = __floats2half2_rn(v0.x, v0.y);
  h1.h = __floats2half2_rn(v0.z, v0.w);
  h2.h = __floats2half2_rn(v1.x, v1.y);
  h3.h = __floats2half2_rn(v1.z, v1.w);
  uv4_t o = {h0.u, h1.u, h2.u, h3.u};
  *(uv4_t*)(d + (size_t)off * 8) = o;
}

// ---------------- MFMA dual node linear (K=128, f16 out) --------------------
// Wave tile: 32 rows x 64 cols; Wh = [2J][128] f16 (rows 0..J-1 = table 1).
// F32IN: A-fragments loaded from f32 X and converted in-register (identical
// rounding to the old pre-convert pass).  No LDS, no barriers.
template <int J, bool F32IN>
__global__ __launch_bounds__(256) void mfma_linear2_k(
    const void* __restrict__ Xin, const __half* __restrict__ Wh,
    const float* __restrict__ b1v, const float* __restrict__ b2v,
    __half* __restrict__ out1, __half* __restrict__ out2, int N) {
  constexpr int CG = (2 * J) / 64;  // 64-col groups across both tables
  int lane = threadIdx.x & 63;
  int wid = __builtin_amdgcn_readfirstlane(
      (int)((blockIdx.x * 256 + threadIdx.x) >> 6));
  int rt = wid / CG;
  int cg = wid - rt * CG;
  int r0 = rt * 32;
  if (r0 >= N) return;

  int koff = (lane >> 4) * 8;           // 8 contiguous k per lane-group
  int row0 = r0 + (lane & 15);
  int row1 = row0 + 16;
  int cr0 = min(row0, N - 1), cr1 = min(row1, N - 1);

  f16x8 a0[4], a1[4];
  if (F32IN) {
    const float* Xf = (const float*)Xin;
    const float* xp0 = Xf + (size_t)cr0 * 128 + koff;
    const float* xp1 = Xf + (size_t)cr1 * 128 + koff;
#pragma unroll
    for (int ks = 0; ks < 4; ++ks) {
      a0[ks] = cvt8(xp0 + ks * 32);
      a1[ks] = cvt8(xp1 + ks * 32);
    }
  } else {
    const __half* Xh = (const __half*)Xin;
    const __half* xp0 = Xh + (size_t)cr0 * 128 + koff;
    const __half* xp1 = Xh + (size_t)cr1 * 128 + koff;
#pragma unroll
    for (int ks = 0; ks < 4; ++ks) {
      a0[ks] = *(const f16x8*)(xp0 + ks * 32);
      a1[ks] = *(const f16x8*)(xp1 + ks * 32);
    }
  }

  bool isT1 = (cg * 64) < J;            // whole 64-col group in one table
  const float* bt = isT1 ? b1v : b2v;
  __half* op = isT1 ? out1 : out2;
  int cbase = cg * 64 - (isT1 ? 0 : J);
  int cl = cbase + (lane & 15);
  int rA = r0 + ((lane >> 4) << 2);

#pragma unroll
  for (int ct = 0; ct < 4; ++ct) {
    int col = cg * 64 + ct * 16 + (lane & 15);
    const __half* wp = Wh + (size_t)col * 128 + koff;
    f16x8 b0 = *(const f16x8*)(wp);
    f16x8 b1_ = *(const f16x8*)(wp + 32);
    f16x8 b2_ = *(const f16x8*)(wp + 64);
    f16x8 b3_ = *(const f16x8*)(wp + 96);
    f32x4 acc0 = {0.f, 0.f, 0.f, 0.f};
    f32x4 acc1 = {0.f, 0.f, 0.f, 0.f};
    acc0 = __builtin_amdgcn_mfma_f32_16x16x32_f16(a0[0], b0, acc0, 0, 0, 0);
    acc1 = __builtin_amdgcn_mfma_f32_16x16x32_f16(a1[0], b0, acc1, 0, 0, 0);
    acc0 = __builtin_amdgcn_mfma_f32_16x16x32_f16(a0[1], b1_, acc0, 0, 0, 0);
    acc1 = __builtin_amdgcn_mfma_f32_16x16x32_f16(a1[1], b1_, acc1, 0, 0, 0);
    acc0 = __builtin_amdgcn_mfma_f32_16x16x32_f16(a0[2], b2_, acc0, 0, 0, 0);
    acc1 = __builtin_amdgcn_mfma_f32_16x16x32_f16(a1[2], b2_, acc1, 0, 0, 0);
    acc0 = __builtin_amdgcn_mfma_f32_16x16x32_f16(a0[3], b3_, acc0, 0, 0, 0);
    acc1 = __builtin_amdgcn_mfma_f32_16x16x32_f16(a1[3], b3_, acc1, 0, 0, 0);

    int cc = cl + ct * 16;
    float bb = bt[cc];
#pragma unroll
    for (int q = 0; q < 4; ++q) {
      int r = rA + q;
      if (r < N) op[(size_t)r * J + cc] = __float2half(acc0[q] + bb);
      int r2 = r + 16;
      if (r2 < N) op[(size_t)r2 * J + cc] = __float2half(acc1[q] + bb);
    }
  }
}

// ---------------- fused GATv2 layer 1 (H=4, C=32, concat) -------------------
// r24 structure: one wave per node, scalar (SGPR) rec loads, broadcast
// gathers (2 ch/lane), CH=8 flat chunks; tail = batched quad (if rem>=4)
// + pairs + single, in edge order.  f16 output.
__global__ __launch_bounds__(128) void gat1_fused_k(
    const int* __restrict__ rowptr, const uint4* __restrict__ erec,
    const __half* __restrict__ xlh, const __half* __restrict__ xrh,
    const float* __restrict__ We, const float* __restrict__ att,
    const float* __restrict__ bias, __half* __restrict__ out, int N) {
  constexpr int CH = 8;
  int lane = threadIdx.x & 63;
  int wave0 = __builtin_amdgcn_readfirstlane(
      (int)((blockIdx.x * blockDim.x + threadIdx.x) >> 6));
  int nwaves = (gridDim.x * blockDim.x) >> 6;
  const __half2* xl2p = (const __half2*)xlh;
  const __half2* xr2p = (const __half2*)xrh;
  __half2* outp = (__half2*)out;
  int c0 = 2 * lane;
  __half2 w0p = __floats2half2_rn(We[c0 * 3 + 0], We[c0 * 3 + 3]);
  __half2 w1p = __floats2half2_rn(We[c0 * 3 + 1], We[c0 * 3 + 4]);
  __half2 w2p = __floats2half2_rn(We[c0 * 3 + 2], We[c0 * 3 + 5]);
  __half2 attp = __floats2half2_rn(att[c0] * LOG2E, att[c0 + 1] * LOG2E);
  __half2 k02 = __floats2half2_rn(0.2f, 0.2f);
  float2 bv = make_float2(bias[c0], bias[c0 + 1]);

  for (int n = wave0; n < N; n += nwaves) {
    __half2 xrp = xr2p[(size_t)n * 64 + lane];
    int beg = rowptr[n], end = rowptr[n + 1];
    int cnt = end - beg;  // deg + 1 (self-loop included)

    float acc0 = 0.f, acc1 = 0.f, den = 0.f;

    auto edge1 = [&](const uint4& rec, __half2 rf) {
      H2U e0, e1, e2;
      e0.u = rec.y; e1.u = rec.z; e2.u = rec.w;
      __half2 m = __hadd2(rf, xrp);
      m = __hfma2(e0.h, w0p, m);
      m = __hfma2(e1.h, w1p, m);
      m = __hfma2(e2.h, w2p, m);
      m = hmax2(m, __hmul2(m, k02));
      float v = row_sum16(dot2f(m, attp, 0.f));
      float ex = fexp2(v);
      float2 rfF = __half22float2(rf);
      den += ex;
      acc0 = fmaf(ex, rfF.x, acc0);
      acc1 = fmaf(ex, rfF.y, acc1);
    };

    int nfull = cnt / CH;
    for (int ch = 0; ch < nfull; ++ch) {
      int b = beg + ch * CH;
      uint4 recs[CH];
#pragma unroll
      for (int j = 0; j < CH; ++j) recs[j] = erec[b + j];
      __half2 r_[CH];
#pragma unroll
      for (int j = 0; j < CH; ++j) {
        int s = __builtin_amdgcn_readfirstlane((int)recs[j].x);
        r_[j] = xl2p[(size_t)s * 64 + lane];
      }
#pragma unroll
      for (int j = 0; j < CH; ++j) edge1(recs[j], r_[j]);
    }
    int gi = beg + nfull * CH;
    // batched quad stage (rem >= 4)
    if (gi + 4 <= end) {
      uint4 recs[4];
#pragma unroll
      for (int j = 0; j < 4; ++j) recs[j] = erec[gi + j];
      __half2 r_[4];
#pragma unroll
      for (int j = 0; j < 4; ++j) {
        int s = __builtin_amdgcn_readfirstlane((int)recs[j].x);
        r_[j] = xl2p[(size_t)s * 64 + lane];
      }
#pragma unroll
      for (int j = 0; j < 4; ++j) edge1(recs[j], r_[j]);
      gi += 4;
    }
    // pairs + optional single
    for (; gi + 2 <= end; gi += 2) {
      uint4 recA = erec[gi];
      uint4 recB = erec[gi + 1];
      int sA = __builtin_amdgcn_readfirstlane((int)recA.x);
      int sB = __builtin_amdgcn_readfirstlane((int)recB.x);
      __half2 rfA = xl2p[(size_t)sA * 64 + lane];
      __half2 rfB = xl2p[(size_t)sB * 64 + lane];
      edge1(recA, rfA);
      edge1(recB, rfB);
    }
    if (gi < end) {
      uint4 rec = erec[gi];
      int s = __builtin_amdgcn_readfirstlane((int)rec.x);
      __half2 rf = xl2p[(size_t)s * 64 + lane];
      edge1(rec, rf);
    }

    float o0 = acc0 / den + bv.x;
    float o1 = acc1 / den + bv.y;
    o0 = o0 > 0.f ? o0 : __expf(o0) - 1.0f;  // ELU
    o1 = o1 > 0.f ? o1 : __expf(o1) - 1.0f;
    H2U o;
    o.h = __floats2half2_rn(o0, o1);
    outp[(size_t)n * 64 + lane] = o.h;
  }
}

// ---------------- fused GATv2 layer 2 (H=1, C=64, mean) ---------------------
// One wave per node; 4 edges/wave (16 lanes each, 4 ch/lane); score reduce =
// row_sum16 only; exp/den amortize 4x.  f32 output.  (r27 version - won.)
__global__ __launch_bounds__(128) void gat2_fused_k(
    const int* __restrict__ rowptr, const uint4* __restrict__ erec,
    const __half* __restrict__ xlh, const __half* __restrict__ xrh,
    const float* __restrict__ We, const float* __restrict__ att,
    const float* __restrict__ bias, float* __restrict__ out, int N) {
  int lane = threadIdx.x & 63;
  int s16 = lane & 15, qr = lane >> 4;  // quarter 0..3
  int wave0 = __builtin_amdgcn_readfirstlane(
      (int)((blockIdx.x * blockDim.x + threadIdx.x) >> 6));
  int nwaves = (gridDim.x * blockDim.x) >> 6;
  int c4 = s16 * 4;  // this lane's 4 channels of 64

  __half2 w0A = __floats2half2_rn(We[(c4 + 0) * 3 + 0], We[(c4 + 1) * 3 + 0]);
  __half2 w0B = __floats2half2_rn(We[(c4 + 2) * 3 + 0], We[(c4 + 3) * 3 + 0]);
  __half2 w1A = __floats2half2_rn(We[(c4 + 0) * 3 + 1], We[(c4 + 1) * 3 + 1]);
  __half2 w1B = __floats2half2_rn(We[(c4 + 2) * 3 + 1], We[(c4 + 3) * 3 + 1]);
  __half2 w2A = __floats2half2_rn(We[(c4 + 0) * 3 + 2], We[(c4 + 1) * 3 + 2]);
  __half2 w2B = __floats2half2_rn(We[(c4 + 2) * 3 + 2], We[(c4 + 3) * 3 + 2]);
  __half2 attA = __floats2half2_rn(att[c4 + 0] * LOG2E, att[c4 + 1] * LOG2E);
  __half2 attB = __floats2half2_rn(att[c4 + 2] * LOG2E, att[c4 + 3] * LOG2E);
  __half2 k02 = __floats2half2_rn(0.2f, 0.2f);
  float4 bvv = make_float4(bias[c4], bias[c4 + 1], bias[c4 + 2], bias[c4 + 3]);

  for (int n = wave0; n < N; n += nwaves) {
    uint2 xu = *(const uint2*)&xrh[(size_t)n * 64 + c4];
    H2U xrA, xrB;
    xrA.u = xu.x; xrB.u = xu.y;
    int beg = rowptr[n], end = rowptr[n + 1];
    int cnt = end - beg;  // deg + 1
    float a0 = 0.f, a1 = 0.f, a2 = 0.f, a3 = 0.f, den = 0.f;

    auto edge4 = [&](const uint4& rec, uint2 gu, bool valid) {
      H2U e0, e1, e2, gA, gB;
      e0.u = rec.y; e1.u = rec.z; e2.u = rec.w;
      gA.u = gu.x; gB.u = gu.y;
      __half2 tA = __hfma2(e2.h, w2A, xrA.h);
      tA = __hfma2(e1.h, w1A, tA);
      tA = __hfma2(e0.h, w0A, tA);
      __half2 mA = __hadd2(gA.h, tA);
      mA = hmax2(mA, __hmul2(mA, k02));
      __half2 tB = __hfma2(e2.h, w2B, xrB.h);
      tB = __hfma2(e1.h, w1B, tB);
      tB = __hfma2(e0.h, w0B, tB);
      __half2 mB = __hadd2(gB.h, tB);
      mB = hmax2(mB, __hmul2(mB, k02));
      float v = dot2f(mB, attB, dot2f(mA, attA, 0.f));
      v = row_sum16(v);
      float ex = valid ? fexp2(v) : 0.f;
      float2 fA = __half22float2(gA.h), fB = __half22float2(gB.h);
      den += ex;
      a0 = fmaf(ex, fA.x, a0);
      a1 = fmaf(ex, fA.y, a1);
      a2 = fmaf(ex, fB.x, a2);
      a3 = fmaf(ex, fB.y, a3);
    };

    int nch = cnt >> 3;  // chunks of 8 edges = 2 quads
    for (int ch = 0; ch < nch; ++ch) {
      int b = beg + ch * 8 + qr;
      uint4 rec[2];
      uint2 gu[2];
#pragma unroll
      for (int j = 0; j < 2; ++j) rec[j] = erec[b + 4 * j];
#pragma unroll
      for (int j = 0; j < 2; ++j)
        gu[j] = *(const uint2*)(xlh + (size_t)rec[j].x * 64 + c4);
#pragma unroll
      for (int j = 0; j < 2; ++j) edge4(rec[j], gu[j], true);
    }
    // tail quads: invalid quarters masked
    for (int gi = beg + nch * 8; gi < end; gi += 4) {
      int idx = gi + qr;
      bool valid = idx < end;
      uint4 rec = erec[valid ? idx : (end - 1)];
      uint2 gu = *(const uint2*)(xlh + (size_t)rec.x * 64 + c4);
      edge4(rec, gu, valid);
    }

    // combine the four quarters
    a0 += __shfl_xor(a0, 16); a0 += __shfl_xor(a0, 32);
    a1 += __shfl_xor(a1, 16); a1 += __shfl_xor(a1, 32);
    a2 += __shfl_xor(a2, 16); a2 += __shfl_xor(a2, 32);
    a3 += __shfl_xor(a3, 16); a3 += __shfl_xor(a3, 32);
    den += __shfl_xor(den, 16); den += __shfl_xor(den, 32);

    if (lane < 16) {
      float4 o;
      o.x = eluf(a0 / den + bvv.x);
      o.y = eluf(a1 / den + bvv.y);
      o.z = eluf(a2 / den + bvv.z);
      o.w = eluf(a3 / den + bvv.w);
      *(float4*)&out[(size_t)n * 64 + c4] = o;
    }
  }
}

// ---------------- fused mean-pool + MLP head (block per graph, 256 thr) -----
__global__ void final_mlp_k(const float* __restrict__ h2, const int* __restrict__ batch,
                            int N, const float* __restrict__ u,
                            const float* __restrict__ W1, const float* __restrict__ b1,
                            const float* __restrict__ Wh, const float* __restrict__ bh,
                            float* __restrict__ out) {
  __shared__ float comb[4][64];
  __shared__ float feat[65];
  __shared__ float z[32];
  int g = blockIdx.x;
  int t = threadIdx.x;  // 256 threads
  int c = t & 63, q = t >> 6;
  int lo, hi;
  {
    int l = 0, h = N;
    while (l < h) { int m = (l + h) >> 1; if (batch[m] < g) l = m + 1; else h = m; }
    lo = l;
    h = N;
    while (l < h) { int m = (l + h) >> 1; if (batch[m] < g + 1) l = m + 1; else h = m; }
    hi = l;
  }
  float a = 0.f;
  for (int nn = lo + q; nn < hi; nn += 4) a += h2[(size_t)nn * 64 + c];
  comb[q][c] = a;
  __syncthreads();
  if (t < 64) {
    float s = comb[0][t] + comb[1][t] + comb[2][t] + comb[3][t];
    float inv = 1.0f / fmaxf((float)(hi - lo), 1.0f);
    feat[t] = s * inv;
    if (t == 0) feat[64] = u[g];
  }
  __syncthreads();
  if (t < 32) {
    float s = b1[t];
    for (int k = 0; k < 65; ++k) s += feat[k] * W1[t * 65 + k];
    z[t] = fmaxf(s, 0.0f);
  }
  __syncthreads();
  if (t < 10) {
    float s = bh[t];
    for (int k = 0; k < 32; ++k) s += z[k] * Wh[t * 32 + k];
    out[g * 10 + t] = s;
  }
}

// ---------------------------------------------------------------------------
extern "C" void kernel_launch(void* const* d_in, const int* in_sizes, int n_in,
                              void* d_out, int out_size, void* d_ws, size_t ws_size,
                              hipStream_t stream) {
  const float* x      = (const float*)d_in[0];
  const int*   eidx   = (const int*)d_in[1];
  const float* eattr  = (const float*)d_in[2];
  const int*   batch  = (const int*)d_in[3];
  const float* u      = (const float*)d_in[4];
  const float* Wl1    = (const float*)d_in[5];
  const float* bl1    = (const float*)d_in[6];
  const float* Wr1    = (const float*)d_in[7];
  const float* br1    = (const float*)d_in[8];
  const float* We1    = (const float*)d_in[9];
  const float* att1   = (const float*)d_in[10];
  const float* b1     = (const float*)d_in[11];
  const float* Wl2    = (const float*)d_in[12];
  const float* bl2    = (const float*)d_in[13];
  const float* Wr2    = (const float*)d_in[14];
  const float* br2    = (const float*)d_in[15];
  const float* We2    = (const float*)d_in[16];
  const float* att2   = (const float*)d_in[17];
  const float* b2     = (const float*)d_in[18];
  const float* W_lin1 = (const float*)d_in[19];
  const float* b_lin1 = (const float*)d_in[20];
  const float* W_head = (const float*)d_in[21];
  const float* b_head = (const float*)d_in[22];

  const int N = in_sizes[0] / 128;
  const int E = in_sizes[1] / 2;
  const int G = in_sizes[4];
  const int* srcp = eidx;
  const int* dstp = eidx + E;

  // ---- workspace layout ----
  __half* bufh = (__half*)d_ws;                     // xl table (N*128 half max)
  __half* bufr = bufh + (size_t)N * 128;            // xr table
  float* buf3 = (float*)(bufr + (size_t)N * 128);   // region: g1h f16 / h2 f32
  __half* g1h = (__half*)buf3;                      // gat1 out f16 [N,128]
  float* h2f = (float*)(g1h + (size_t)N * 128);     // gat2 out f32 [N,64]
  uint4* erec = (uint4*)(buf3 + (size_t)N * 128);   // E+N records (16B)
  int* rank   = (int*)(erec + ((size_t)E + N));     // E
  int* deg    = rank + E;                           // N
  int* rowptr = deg + N;                            // N+1
  int* bsum   = rowptr + N + 1;                     // 256
  uintptr_t wtop = ((uintptr_t)(bsum + 256) + 15) & ~(uintptr_t)15;
  __half* wh1 = (__half*)wtop;                      // [256][128] f16 = 64 KB
  __half* wh2 = wh1 + 32768;                        // [128][128] f16 = 32 KB

  const int nb = (N + 255) / 256;
  const int gat_blocks = (N + 1) / 2;               // 1 wave/node, 128-thr blks
  const int rt = (N + 31) / 32;                     // 32-row MFMA tiles

  // ---- weight tables + layer-1 MFMA linear (reads f32 X directly) ----
  cvt_w_all_k<<<24, 256, 0, stream>>>(Wl1, Wr1, Wl2, Wr2, wh1, wh2);
  mfma_linear2_k<128, true><<<rt, 256, 0, stream>>>(x, wh1, bl1, br1,
                                                    bufh, bufr, N);

  // ---- CSR build ----
  (void)hipMemsetAsync(deg, 0, sizeof(int) * (size_t)N, stream);
  hist_k<<<(E + 255) / 256, 256, 0, stream>>>(dstp, deg, rank, E);
  blocksum_k<<<nb, 256, 0, stream>>>(deg, bsum, N);
  writeptr_k<<<nb, 256, 0, stream>>>(deg, bsum, rowptr, N, E);
  fill_k<<<(E + 255) / 256, 256, 0, stream>>>(srcp, dstp, eattr, rowptr, rank, erec, E);
  loopattr_k<<<(N * 64 + 255) / 256, 256, 0, stream>>>(rowptr, erec, N);

  // ---- layer 1 attention ----
  gat1_fused_k<<<gat_blocks, 128, 0, stream>>>(rowptr, erec, bufh, bufr,
                                               We1, att1, b1, g1h, N);

  // ---- layer 2 linear (MFMA) + attention ----
  mfma_linear2_k<64, false><<<(rt * 2 + 3) / 4, 256, 0, stream>>>(g1h, wh2,
                                                                  bl2, br2,
                                                                  bufh, bufr, N);
  gat2_fused_k<<<gat_blocks, 128, 0, stream>>>(rowptr, erec, bufh, bufr,
                                               We2, att2, b2, h2f, N);

  // ---- fused pool + head ----
  final_mlp_k<<<G, 256, 0, stream>>>(h2f, batch, N, u, W_lin1, b_lin1, W_head, b_head,
                                     (float*)d_out);
}